// Round 4
// baseline (140.083 us; speedup 1.0000x reference)
//
#include <hip/hip_runtime.h>

#define BATCH 500000
#define NF 20
#define NC 8
#define BLOCK 256

typedef float v4f __attribute__((ext_vector_type(4)));

__global__ __launch_bounds__(BLOCK) void nb_kernel(const float* __restrict__ x,
                                                   float* __restrict__ out) {
    int row = blockIdx.x * blockDim.x + threadIdx.x;
    if (row >= BATCH) return;

    // ---- load 40 floats (10 dwordx4) for this row; streaming -> nontemporal ----
    const v4f* xv = (const v4f*)(x + (size_t)row * (2 * NF));
    float feats[NF], mask[NF];
    #pragma unroll
    for (int i = 0; i < 5; ++i) {
        v4f v = __builtin_nontemporal_load(xv + i);
        feats[4*i+0] = v.x; feats[4*i+1] = v.y; feats[4*i+2] = v.z; feats[4*i+3] = v.w;
    }
    #pragma unroll
    for (int i = 0; i < 5; ++i) {
        v4f v = __builtin_nontemporal_load(xv + 5 + i);
        mask[4*i+0] = v.x; mask[4*i+1] = v.y; mask[4*i+2] = v.z; mask[4*i+3] = v.w;
    }

    // indicator term per feature (contribution of a non-Gaussian feature)
    float term[NF];
    #pragma unroll
    for (int f = 0; f < NF; ++f) {
        float ind = (feats[f] >= 0.0f && feats[f] < 1.0f) ? 1.0f : 0.0f;
        term[f] = (mask[f] > 0.0f) ? ind : 1.0f;
    }

    // prefix/suffix products: class y's non-Gaussian product = pre[y]*suf[y+3]
    float pre[NF + 1], suf[NF + 1];
    pre[0] = 1.0f;
    #pragma unroll
    for (int f = 0; f < NF; ++f) pre[f + 1] = pre[f] * term[f];
    suf[NF] = 1.0f;
    #pragma unroll
    for (int f = NF - 1; f >= 0; --f) suf[f] = suf[f + 1] * term[f];

    const float inv_std = 1.0f / 0.3f;
    const float k_pdf   = 0.3989422804014327f / 0.3f;   // INV_SQRT_2PI / STD

    float probs[NC];
    float total = 0.0f;
    #pragma unroll
    for (int y = 0; y < NC; ++y) {
        float p = pre[y] * suf[y + 3];
        #pragma unroll
        for (int j = 0; j < 3; ++j) {
            int   f = y + j;
            float m = (float)((y >> j) & 1);
            float z = (feats[f] - m) * inv_std;
            float pdf = __expf(-0.5f * z * z) * k_pdf;
            p *= (mask[f] > 0.0f) ? pdf : 1.0f;
        }
        p *= 0.125f;                 // 1/NC before normalizer floor (matches reference)
        probs[y] = p;
        total += p;
    }

    float inv = 1.0f / fmaxf(total, 1e-8f);

    v4f o0 = { probs[0] * inv, probs[1] * inv, probs[2] * inv, probs[3] * inv };
    v4f o1 = { probs[4] * inv, probs[5] * inv, probs[6] * inv, probs[7] * inv };
    v4f* ov = (v4f*)(out + (size_t)row * NC);
    __builtin_nontemporal_store(o0, ov + 0);
    __builtin_nontemporal_store(o1, ov + 1);
}

extern "C" void kernel_launch(void* const* d_in, const int* in_sizes, int n_in,
                              void* d_out, int out_size, void* d_ws, size_t ws_size,
                              hipStream_t stream) {
    const float* x = (const float*)d_in[0];
    float* out = (float*)d_out;
    int blocks = (BATCH + BLOCK - 1) / BLOCK;
    nb_kernel<<<blocks, BLOCK, 0, stream>>>(x, out);
}

// Round 5
// 117.083 us; speedup vs baseline: 1.1964x; 1.1964x over previous
//
#include <hip/hip_runtime.h>

#define BATCH 500000
#define NF 20
#define NC 8
#define BLOCK 256

__global__ __launch_bounds__(BLOCK) void nb_kernel(const float* __restrict__ x,
                                                   float* __restrict__ out) {
    int row = blockIdx.x * blockDim.x + threadIdx.x;
    if (row >= BATCH) return;

    // Per-thread row loads: each wave's 10 dwordx4 cover a contiguous 10 KB
    // window; L1 absorbs the intra-window re-touches (measured: cached loads
    // 117.9us total vs nontemporal 140.1us — do NOT mark these nt).
    const float4* xv = (const float4*)(x + (size_t)row * (2 * NF));
    float feats[NF], mask[NF];
    #pragma unroll
    for (int i = 0; i < 5; ++i) {
        float4 v = xv[i];
        feats[4*i+0] = v.x; feats[4*i+1] = v.y; feats[4*i+2] = v.z; feats[4*i+3] = v.w;
    }
    #pragma unroll
    for (int i = 0; i < 5; ++i) {
        float4 v = xv[5 + i];
        mask[4*i+0] = v.x; mask[4*i+1] = v.y; mask[4*i+2] = v.z; mask[4*i+3] = v.w;
    }

    // indicator term per feature (contribution of a non-Gaussian feature)
    float term[NF];
    #pragma unroll
    for (int f = 0; f < NF; ++f) {
        float ind = (feats[f] >= 0.0f && feats[f] < 1.0f) ? 1.0f : 0.0f;
        term[f] = (mask[f] > 0.0f) ? ind : 1.0f;
    }

    // prefix/suffix products: class y's non-Gaussian product = pre[y]*suf[y+3]
    float pre[NF + 1], suf[NF + 1];
    pre[0] = 1.0f;
    #pragma unroll
    for (int f = 0; f < NF; ++f) pre[f + 1] = pre[f] * term[f];
    suf[NF] = 1.0f;
    #pragma unroll
    for (int f = NF - 1; f >= 0; --f) suf[f] = suf[f + 1] * term[f];

    const float inv_std = 1.0f / 0.3f;
    const float k_pdf   = 0.3989422804014327f / 0.3f;   // INV_SQRT_2PI / STD

    float probs[NC];
    float total = 0.0f;
    #pragma unroll
    for (int y = 0; y < NC; ++y) {
        float p = pre[y] * suf[y + 3];
        #pragma unroll
        for (int j = 0; j < 3; ++j) {
            int   f = y + j;
            float m = (float)((y >> j) & 1);
            float z = (feats[f] - m) * inv_std;
            float pdf = __expf(-0.5f * z * z) * k_pdf;
            p *= (mask[f] > 0.0f) ? pdf : 1.0f;
        }
        p *= 0.125f;                 // 1/NC before normalizer floor (matches reference)
        probs[y] = p;
        total += p;
    }

    float inv = 1.0f / fmaxf(total, 1e-8f);

    float4 o0 = make_float4(probs[0] * inv, probs[1] * inv, probs[2] * inv, probs[3] * inv);
    float4 o1 = make_float4(probs[4] * inv, probs[5] * inv, probs[6] * inv, probs[7] * inv);
    float4* ov = (float4*)(out + (size_t)row * NC);
    ov[0] = o0;
    ov[1] = o1;
}

extern "C" void kernel_launch(void* const* d_in, const int* in_sizes, int n_in,
                              void* d_out, int out_size, void* d_ws, size_t ws_size,
                              hipStream_t stream) {
    const float* x = (const float*)d_in[0];
    float* out = (float*)d_out;
    int blocks = (BATCH + BLOCK - 1) / BLOCK;
    nb_kernel<<<blocks, BLOCK, 0, stream>>>(x, out);
}